// Round 8
// baseline (54.819 us; speedup 1.0000x reference)
//
#include <hip/hip_runtime.h>

// SSIM loss, fused separable 11x11 Gaussian conv + SSIM map + mean.
// Images: 32 x 1 x 512 x 512 fp32. Output: 1 fp32 scalar.
//
// R8 = R7 + persistent blocks with register-prefetch software pipeline.
// 768 persistent blocks (3/CU); each processes tiles b, b+768, ... Per
// tile: issue tile t+1's global loads into regs BEFORE stage-2 compute
// (HBM latency ~900cy hides under stage2 ~1100cy VALU), write regs->LDS
// during stage-3 (raw buffer free after stage-2 barrier). Steady-state
// staging latency fully hidden; SSIM partial accumulated per block.
//
// Stage 2: horizontal Gaussian on {a,b,p^2,m^2} from LDS -> packed bf16 LDS
//   (4-field algebra: p=a+b, m=a-b; E[a2]+E[b2]=(cp+cm)/2, E[ab]=(cp-cm)/4)
// Stage 3: vertical Gaussian in registers -> SSIM -> accumulate
// Kernel 2: deterministic tree reduce of 768 partials -> scalar.

#define IMGW 512
#define IMGH 512
#define NIMG 32
#define TW 32
#define TH 64
#define IN_H 74        // TH + 10
#define IN_W 44        // LDS row stride (dwords); cols 0..41 used, 42..43 pad
#define NCHUNK (IN_H * 11)   // 814 16B chunks per image tile
#define NBX 16         // 512 / TW
#define NBY 8          // 512 / TH
#define NTILES (NBX * NBY * NIMG)   // 4096
#define GRID 768       // persistent blocks, 3 per CU

typedef float float4a __attribute__((ext_vector_type(4)));
typedef float float2a __attribute__((ext_vector_type(2)));

__device__ __forceinline__ uint32_t pkbf(float lo, float hi) {
  uint32_t a = __builtin_bit_cast(uint32_t, lo);
  uint32_t b = __builtin_bit_cast(uint32_t, hi);
  return (a >> 16) | (b & 0xffff0000u);
}
__device__ __forceinline__ float up_lo(uint32_t w) {
  return __builtin_bit_cast(float, w << 16);
}
__device__ __forceinline__ float up_hi(uint32_t w) {
  return __builtin_bit_cast(float, w & 0xffff0000u);
}

__global__ __launch_bounds__(256, 3) void ssim_main(
    const float* __restrict__ img1, const float* __restrict__ img2,
    float* __restrict__ partial) {
  __shared__ float4a sA4[IN_H * 11];   // raw img1 tile, 13.0 KB
  __shared__ float4a sB4[IN_H * 11];   // raw img2 tile, 13.0 KB
  __shared__ uint32_t hAB[IN_H][TW];   // (conv a, conv b)    9.25 KB
  __shared__ uint32_t hPM[IN_H][TW];   // (conv p^2, conv m^2) 9.25 KB
  __shared__ float sWave[4];
  float* sA = (float*)sA4;
  float* sB = (float*)sB4;

  // Unnormalized Gaussian, 2*sigma^2 = 4 (faithful to reference).
  constexpr float g[11] = {0.0019304541f, 0.018315639f, 0.10539922f,
                           0.36787944f,   0.7788008f,   1.0f,
                           0.7788008f,    0.36787944f,  0.10539922f,
                           0.018315639f,  0.0019304541f};
  constexpr float C1v = 6.5025f;    // (0.01*255)^2
  constexpr float C2v = 58.5225f;   // (0.03*255)^2

  const int tid = threadIdx.x;

  // Prefetch registers: 8 x float4 = 32 VGPRs + dests.
  float4a pa[4], pb[4];
  int pdst[4];

  auto issue_loads = [&](int tile) {
    int img = tile >> 7;          // 128 tiles per image
    int rem = tile & 127;
    int by = rem >> 4;
    int bx = rem & 15;
    int x0 = bx * TW - 5;
    int y0 = by * TH - 5;
    const float* __restrict__ p1 = img1 + (size_t)img * (IMGW * IMGH);
    const float* __restrict__ p2 = img2 + (size_t)img * (IMGW * IMGH);
#pragma unroll
    for (int i = 0; i < 4; ++i) {
      int ch = tid + 256 * i;
      bool live = (ch < NCHUNK);
      int r = ch / 11;
      int cg = ch - r * 11;
      int gy = y0 + r;
      int gx = x0 + 4 * cg;
      pdst[i] = live ? (ch * 4) : -1;   // LDS dword addr == r*44 + 4*cg
      bool rowok = live && (gy >= 0) && (gy < IMGH);
      if (rowok && gx >= 0 && gx + 3 < IMGW) {
        pa[i] = *(const float4a*)(p1 + gy * IMGW + gx);
        pb[i] = *(const float4a*)(p2 + gy * IMGW + gx);
      } else {
#pragma unroll
        for (int j = 0; j < 4; ++j) {
          int xx = gx + j;
          bool ok = rowok && (xx >= 0) && (xx < IMGW);
          int off = gy * IMGW + xx;
          pa[i][j] = ok ? p1[off] : 0.0f;
          pb[i][j] = ok ? p2[off] : 0.0f;
        }
      }
    }
  };
  auto write_lds = [&]() {
#pragma unroll
    for (int i = 0; i < 4; ++i) {
      if (pdst[i] >= 0) {
        *(float4a*)&sA[pdst[i]] = pa[i];
        *(float4a*)&sB[pdst[i]] = pb[i];
      }
    }
  };

  // Prologue: stage tile 0 (latency exposed once per block).
  issue_loads(blockIdx.x);
  write_lds();
  __syncthreads();

  float tsum = 0.f;
  for (int tile = blockIdx.x; tile < NTILES;) {
    int next = tile + GRID;
    bool more = (next < NTILES);
    if (more) issue_loads(next);   // in flight during stage 2

    // ---- Stage 2: horizontal pass from LDS, 4 outputs/task ----
    for (int idx = tid; idx < IN_H * (TW / 4); idx += 256) {
      int r = idx >> 3;
      int c0 = (idx & 7) << 2;
      int base = r * IN_W + c0;   // 16B-aligned
      float av[14], bv[14];
      {
        float4a a0 = *(const float4a*)&sA[base];
        float4a a1 = *(const float4a*)&sA[base + 4];
        float4a a2 = *(const float4a*)&sA[base + 8];
        float2a a3 = *(const float2a*)&sA[base + 12];
        float4a b0 = *(const float4a*)&sB[base];
        float4a b1 = *(const float4a*)&sB[base + 4];
        float4a b2 = *(const float4a*)&sB[base + 8];
        float2a b3 = *(const float2a*)&sB[base + 12];
#pragma unroll
        for (int i = 0; i < 4; ++i) {
          av[i] = a0[i]; av[4 + i] = a1[i]; av[8 + i] = a2[i];
          bv[i] = b0[i]; bv[4 + i] = b1[i]; bv[8 + i] = b2[i];
        }
        av[12] = a3[0]; av[13] = a3[1];
        bv[12] = b3[0]; bv[13] = b3[1];
      }
      float pv[14], mv[14];
#pragma unroll
      for (int k = 0; k < 14; ++k) {
        float p = av[k] + bv[k];
        float m = av[k] - bv[k];
        pv[k] = p * p;
        mv[k] = m * m;
      }
      float sa[4], sb[4], sp[4], sm[4];
#pragma unroll
      for (int o = 0; o < 4; ++o) {
        float ta = 0.f, tb = 0.f, tp = 0.f, tm = 0.f;
#pragma unroll
        for (int k = 0; k < 11; ++k) {
          float w = g[k];
          ta = fmaf(w, av[o + k], ta);
          tb = fmaf(w, bv[o + k], tb);
          tp = fmaf(w, pv[o + k], tp);
          tm = fmaf(w, mv[o + k], tm);
        }
        sa[o] = ta; sb[o] = tb; sp[o] = tp; sm[o] = tm;
      }
      uint4 wab, wpm;
      wab.x = pkbf(sa[0], sb[0]); wab.y = pkbf(sa[1], sb[1]);
      wab.z = pkbf(sa[2], sb[2]); wab.w = pkbf(sa[3], sb[3]);
      wpm.x = pkbf(sp[0], sm[0]); wpm.y = pkbf(sp[1], sm[1]);
      wpm.z = pkbf(sp[2], sm[2]); wpm.w = pkbf(sp[3], sm[3]);
      *(uint4*)&hAB[r][c0] = wab;
      *(uint4*)&hPM[r][c0] = wpm;
    }
    __syncthreads();   // stage2 done: raw consumed, h ready

    // ---- Stage 3: vertical pass in registers, 8 rows/thread ----
    {
      const int c = tid & 31;
      const int r0 = (tid >> 5) << 3;  // 0..56
      float mu1[8], mu2[8], qp[8], qm[8];
      {
        float m1[18], m2[18];
#pragma unroll
        for (int k = 0; k < 18; ++k) {
          uint32_t w = hAB[r0 + k][c];
          m1[k] = up_lo(w);
          m2[k] = up_hi(w);
        }
#pragma unroll
        for (int o = 0; o < 8; ++o) {
          float s = 0.f, t = 0.f;
#pragma unroll
          for (int k = 0; k < 11; ++k) {
            s = fmaf(g[k], m1[o + k], s);
            t = fmaf(g[k], m2[o + k], t);
          }
          mu1[o] = s; mu2[o] = t;
        }
#pragma unroll
        for (int k = 0; k < 18; ++k) {
          uint32_t w = hPM[r0 + k][c];
          m1[k] = up_lo(w);
          m2[k] = up_hi(w);
        }
#pragma unroll
        for (int o = 0; o < 8; ++o) {
          float s = 0.f, t = 0.f;
#pragma unroll
          for (int k = 0; k < 11; ++k) {
            s = fmaf(g[k], m1[o + k], s);
            t = fmaf(g[k], m2[o + k], t);
          }
          qp[o] = s; qm[o] = t;
        }
      }
#pragma unroll
      for (int o = 0; o < 8; ++o) {
        float m1 = mu1[o], m2 = mu2[o];
        float sumsq = 0.5f * (qp[o] + qm[o]);   // E[a^2] + E[b^2]
        float eab = 0.25f * (qp[o] - qm[o]);    // E[ab]
        float m1s = m1 * m1, m2s = m2 * m2, m12 = m1 * m2;
        float sg12 = eab - m12;
        float sgsum = sumsq - m1s - m2s;        // sigma1 + sigma2
        float num = (2.0f * m12 + C1v) * (2.0f * sg12 + C2v);
        float den = (m1s + m2s + C1v) * (sgsum + C2v);
        float r = num * __builtin_amdgcn_rcpf(den);
        if (!__builtin_isfinite(r)) r = 0.0f;   // guard singular pixels
        tsum += r;
      }
    }

    if (more) write_lds();   // raw buffer free; loads long since landed
    __syncthreads();         // h consumed + raw[t+1] visible
    tile = next;
  }

  // ---- block reduction (deterministic) ----
#pragma unroll
  for (int off = 32; off > 0; off >>= 1) tsum += __shfl_down(tsum, off, 64);
  if ((tid & 63) == 0) sWave[tid >> 6] = tsum;
  __syncthreads();
  if (tid == 0) {
    partial[blockIdx.x] = sWave[0] + sWave[1] + sWave[2] + sWave[3];
  }
}

__global__ __launch_bounds__(256) void ssim_reduce(
    const float* __restrict__ partial, float* __restrict__ out) {
  const int tid = threadIdx.x;
  float s = 0.f;
  for (int i = tid; i < GRID; i += 256) s += partial[i];
#pragma unroll
  for (int off = 32; off > 0; off >>= 1) s += __shfl_down(s, off, 64);
  __shared__ float sw[4];
  if ((tid & 63) == 0) sw[tid >> 6] = s;
  __syncthreads();
  if (tid == 0) {
    float tot = sw[0] + sw[1] + sw[2] + sw[3];
    // mean((1 - ssim)/2) = 0.5 * (1 - mean(ssim))
    float val = 0.5f * (1.0f - tot * (1.0f / (32.0f * 512.0f * 512.0f)));
    if (!__builtin_isfinite(val)) val = 0.0f;
    out[0] = val;
  }
}

extern "C" void kernel_launch(void* const* d_in, const int* in_sizes, int n_in,
                              void* d_out, int out_size, void* d_ws,
                              size_t ws_size, hipStream_t stream) {
  const float* img1 = (const float*)d_in[0];
  const float* img2 = (const float*)d_in[1];
  float* partial = (float*)d_ws;  // 768 floats
  float* out = (float*)d_out;

  hipLaunchKernelGGL(ssim_main, dim3(GRID), dim3(256), 0, stream, img1, img2,
                     partial);
  hipLaunchKernelGGL(ssim_reduce, dim3(1), dim3(256), 0, stream, partial, out);
}